// Round 8
// baseline (341.290 us; speedup 1.0000x reference)
//
#include <hip/hip_runtime.h>

// ReconPhongIF: Phong shading with ray-marched shadows.
// R8 = R6 (persistent pools, global fp32 gathers, seq pop) + latency fixes:
//  1) ILP x2: each lane marches TWO rays; step bodies are unmasked (dead
//     lanes carry benign dummy state, addresses always clamped) so both
//     4-load gather sets issue under a full exec mask -> 8 outstanding
//     loads/lane. Kill/result resolution stays predicated on `has` ->
//     decision function identical to reference.
//  2) XCD-affine swizzle: batch = ((blk&7)<<2)|((blk>>3)&3) pins each
//     batch's 64 blocks to one XCD; 256KB image x 4 batches = 1MB resident
//     per XCD L2 -> kills the cross-XCD refetch (R6: FETCH 47MB = 6x image).
//  3) Refill (ballot+LDS atomic+shfl) amortized to every 4th iteration;
//     termination only checked on refill iterations (no livelock).
// R7 lesson: LDS-image scatter = 7.1M bank-conflict cycles + 1 block/CU.
// Ray decisions bit-identical to reference: sequential pos+=step fp32 adds,
// guarded rcp+Newton fast sample, exact-IEEE fallback inside guard band;
// z-exit floor 0.75-1e-6 provably can't change any decision.

#define SDIM 256
#define SS   (SDIM * SDIM)
#define TAN_T 0.08748866352592401      // tan(5 deg) in double
#define STEPC (2.0f / 255.0f)          // linspace(-1,1,256) step
#define POOL  1024                     // rays per block (4 rows)
#define MDV   (0.75f - 1e-6f)          // early-exit floor (depth >= 0.75 by domain)

// ---------------- exact reference test (bit-identical fallback) -------------
__device__ __forceinline__ bool exact_ref_test(float px, float py, float pz,
                                               const float* __restrict__ im) {
#pragma clang fp contract(off)
    const float T = (float)TAN_T;
    const float gx = (px / pz) / T;
    const float gy = (py / pz) / T;
    const float x = (gx + 1.0f) * 128.0f - 0.5f;
    const float y = (gy + 1.0f) * 128.0f - 0.5f;
    const float xo = floorf(x), yo = floorf(y);
    const float wx = x - xo, wy = y - yo;
    const int ex0 = (int)fminf(fmaxf(xo, -300.0f), 300.0f);
    const int ey0 = (int)fminf(fmaxf(yo, -300.0f), 300.0f);
    const int ex0c = min(max(ex0, 0), 255), ex1c = min(max(ex0 + 1, 0), 255);
    const int ey0c = min(max(ey0, 0), 255), ey1c = min(max(ey0 + 1, 0), 255);
    const float e00 = im[(ey0c << 8) + ex0c];
    const float e01 = im[(ey0c << 8) + ex1c];
    const float e10 = im[(ey1c << 8) + ex0c];
    const float e11 = im[(ey1c << 8) + ex1c];
    float s = e00 * (1.0f - wx) * (1.0f - wy);
    s = s + e01 * wx * (1.0f - wy);
    s = s + e10 * (1.0f - wx) * wy;
    s = s + e11 * wx * wy;
    return (s - pz) < 0.0f;
}

// unmasked-safe sample: finite inputs -> clamped addresses; returns diff & guard
struct Smp { float diff, guard, xf, yf; };
__device__ __forceinline__ Smp sample4(float px, float py, float pz,
                                       const float* __restrict__ im) {
#pragma clang fp contract(off)
    const float K = (float)(128.0 / TAN_T);
    float inv = __builtin_amdgcn_rcpf(pz);
    inv = fmaf(fmaf(-pz, inv, 1.0f), inv, inv);
    const float xf = fmaf(px * inv, K, 127.5f);
    const float yf = fmaf(py * inv, K, 127.5f);
    const float x0ff = floorf(xf);
    const float y0ff = floorf(yf);
    const float wxf = xf - x0ff;
    const float wyf = yf - y0ff;
    // pre-clamp in float so cvt is defined even for dummy-lane state
    const int x0 = (int)fminf(fmaxf(x0ff, -300.0f), 300.0f);
    const int y0 = (int)fminf(fmaxf(y0ff, -300.0f), 300.0f);
    const int x0c = min(max(x0, 0), 255), x1c = min(max(x0 + 1, 0), 255);
    const int y0c = min(max(y0, 0), 255), y1c = min(max(y0 + 1, 0), 255);
    const int r0 = y0c << 8, r1 = y1c << 8;
    const float v00 = im[r0 + x0c];
    const float v01 = im[r0 + x1c];
    const float v10 = im[r1 + x0c];
    const float v11 = im[r1 + x1c];
    const float omx = 1.0f - wxf, omy = 1.0f - wyf;
    const float t0 = fmaf(v01, wxf, v00 * omx);
    const float t1 = fmaf(v11, wxf, v10 * omx);
    const float sF = fmaf(t1, wyf, t0 * omy);
    Smp s;
    s.diff  = sF - pz;
    s.guard = fmaf(fabsf(xf) + fabsf(yf), 6e-7f, 1e-5f);
    s.xf = xf; s.yf = yf;
    return s;
}

// ---------------- stage 1: persistent-pool march, 2 rays/lane ----------------
__global__ __launch_bounds__(256) void shadow_march(const float* __restrict__ depth,
                                                    const float* __restrict__ light,
                                                    unsigned char* __restrict__ shmap) {
#pragma clang fp contract(off)
    const int blk = blockIdx.x;
    // XCD-affine: all 64 blocks of a batch share blk%8 -> same XCD L2
    const int b     = ((blk & 7) << 2) | ((blk >> 3) & 3);
    const int chunk = blk >> 5;            // 0..63
    const int rbase = chunk * POOL;        // 4 contiguous rows
    const float* im = depth + (size_t)b * SS;
    const int tid = threadIdx.x;
    const int lane = tid & 63;
    const float T = (float)TAN_T;

    // per-batch params (uniform; exact reference op order)
    const float lx = light[b * 2 + 0];
    const float ly = light[b * 2 + 1];
    float n2 = lx * lx;
    n2 = n2 + ly * ly;
    n2 = n2 + 1.0f;
    const float nr = sqrtf(n2);
    const float sx = (-(lx / nr)) / 256.0f;
    const float sy = (-(ly / nr)) / 256.0f;
    const float sz = (-(1.0f / nr)) / 256.0f;

    __shared__ float         dcache[POOL];
    __shared__ unsigned char res[POOL];
    __shared__ int           popc;
    if (tid == 0) popc = 0;
#pragma unroll
    for (int u = 0; u < POOL / 256; ++u) dcache[tid + u * 256] = im[rbase + tid + u * 256];
    __syncthreads();

    // two ray slots per lane
    bool hasA = false, hasB = false, doneA = false, doneB = false;
    float pxA = 0.0f, pyA = 0.0f, pzA = 1.0f;
    float pxB = 0.0f, pyB = 0.0f, pzB = 1.0f;
    int rrA = 0, rrB = 0, kA = 0, kB = 0;

#define REFILL(has, done, px, py, pz, rr, kk)                                        \
    {                                                                                \
        const bool need = (!has) && (!done);                                         \
        const unsigned long long mneed = __ballot(need);                             \
        if (mneed != 0ull) {                                                         \
            if (need) {                                                              \
                const int leader = (int)__ffsll(mneed) - 1;                          \
                int base = 0;                                                        \
                if (lane == leader) base = atomicAdd(&popc, __popcll(mneed));        \
                base = __shfl(base, leader, 64);                                     \
                const int p = base + __popcll(mneed & ((1ull << (unsigned)lane) - 1ull)); \
                if (p < POOL) {                                                      \
                    const float d = dcache[p];                                       \
                    const int gidx = rbase + p;                                      \
                    const int i = gidx >> 8, j = gidx & 255;                         \
                    const float cj = (-1.0f + (float)j * STEPC) * T;                 \
                    const float ci = (-1.0f + (float)i * STEPC) * T;                 \
                    px = cj * d; py = ci * d; pz = d;                                \
                    rr = p; kk = 256; has = true;                                    \
                } else {                                                             \
                    done = true;                                                     \
                }                                                                    \
            }                                                                        \
        }                                                                            \
    }

    int it = 0;
#pragma unroll 1
    while (true) {
        if ((it & 3) == 0) {
            REFILL(hasA, doneA, pxA, pyA, pzA, rrA, kA);
            REFILL(hasB, doneB, pxB, pyB, pzB, rrB, kB);
            if (__ballot(hasA || hasB) == 0ull) break;
        }
        ++it;
        // ---- unmasked advance (dummy lanes: benign finite state) ----
        pxA += sx; pyA += sy; pzA += sz; --kA;
        pxB += sx; pyB += sy; pzB += sz; --kB;
        // ---- both gather sets issue under full exec mask (8 loads) ----
        const Smp sA = sample4(pxA, pyA, pzA, im);
        const Smp sB = sample4(pxB, pyB, pzB, im);
        // ---- resolve A ----
        {
            bool shf = sA.diff < 0.0f;
            if (__builtin_expect(hasA && fabsf(sA.diff) <= sA.guard, 0))
                shf = exact_ref_test(pxA, pyA, pzA, im);
            const bool z = pzA <= MDV;
            if (hasA && (z || shf || kA == 0)) {
                res[rrA] = shf ? (unsigned char)1 : (unsigned char)0;  // z => shf false (proven)
                hasA = false; pxA = 0.0f; pyA = 0.0f; pzA = 1.0f;
            }
        }
        // ---- resolve B ----
        {
            bool shf = sB.diff < 0.0f;
            if (__builtin_expect(hasB && fabsf(sB.diff) <= sB.guard, 0))
                shf = exact_ref_test(pxB, pyB, pzB, im);
            const bool z = pzB <= MDV;
            if (hasB && (z || shf || kB == 0)) {
                res[rrB] = shf ? (unsigned char)1 : (unsigned char)0;
                hasB = false; pxB = 0.0f; pyB = 0.0f; pzB = 1.0f;
            }
        }
    }
#undef REFILL
    __syncthreads();
    // coalesced flush: 1024 result bytes = 256 dwords
    ((unsigned int*)(shmap + (size_t)b * SS + rbase))[tid] = ((const unsigned int*)res)[tid];
}

// ---------------- stage 2: blur + Phong composition ----------------
__device__ __constant__ float W1[7] = {
    0.07015933f, 0.13107488f, 0.19071282f, 0.21610594f,
    0.19071282f, 0.13107488f, 0.07015933f
};

__device__ __forceinline__ float fpow(float x, float p) {
    return __builtin_amdgcn_exp2f(p * __builtin_amdgcn_logf(x));
}
__device__ __forceinline__ float ftanh(float x) {
    const float e = __builtin_amdgcn_exp2f(x * 2.8853900817779268f);
    return (e - 1.0f) * __builtin_amdgcn_rcpf(e + 1.0f);
}

__global__ __launch_bounds__(256) void compose_kernel(const float* __restrict__ netA,
                                                      const float* __restrict__ netL,
                                                      const float* __restrict__ nrm,
                                                      const float* __restrict__ light,
                                                      const unsigned char* __restrict__ shmap,
                                                      float* __restrict__ out) {
    __shared__ float tile[22][23];

    const int b  = blockIdx.z;
    const int tx = threadIdx.x & 15;
    const int ty = threadIdx.x >> 4;
    const int j0 = blockIdx.x * 16;
    const int i0 = blockIdx.y * 16;

    const unsigned char* shb = shmap + (size_t)b * SS;
    for (int idx = threadIdx.x; idx < 22 * 22; idx += 256) {
        const int r = idx / 22, c = idx - r * 22;
        const int gi = i0 - 3 + r, gj = j0 - 3 + c;
        float v = 0.0f;
        if (gi >= 0 && gi < SDIM && gj >= 0 && gj < SDIM) v = (float)shb[gi * SDIM + gj];
        tile[r][c] = v;
    }
    __syncthreads();

    const int i = i0 + ty;
    const int j = j0 + tx;

    float shadow_s = 0.0f;
#pragma unroll
    for (int dy = 0; dy < 7; ++dy) {
        float rs = 0.0f;
#pragma unroll
        for (int dx = 0; dx < 7; ++dx) rs += W1[dx] * tile[ty + dy][tx + dx];
        shadow_s += W1[dy] * rs;
    }

    const float l0 = tanhf(netL[b * 6 + 0]);
    const float l1 = tanhf(netL[b * 6 + 1]);
    const float l2 = tanhf(netL[b * 6 + 2]);
    const float l5 = tanhf(netL[b * 6 + 5]);
    const float e  = l0 * 0.5f + 0.5f;
    const float f  = e * (float)10.313708498984761 + 1.0f;
    const float spec_alpha    = f * f;
    const float spec_strength = (l5 * 0.5f + 0.5f) * 0.5f;
    const float light_a = l1 / 2.0f + 0.5f;
    const float light_b = l2 / 2.0f + 0.5f;

    const float lx = light[b * 2 + 0];
    const float ly = light[b * 2 + 1];
    const float ln = sqrtf(lx * lx + ly * ly + 1.0f);
    const float ldx = lx / ln, ldy = ly / ln, ldz = 1.0f / ln;

    const float T = (float)TAN_T;
    const float xsj = (-1.0f + (float)(SDIM - 1 - j) * STEPC) * T;
    const float xsi = (-1.0f + (float)(SDIM - 1 - i) * STEPC) * T;
    const float vn = sqrtf(xsj * xsj + xsi * xsi + 1.0f);
    const float vd0 = xsj / vn, vd1 = xsi / vn, vd2 = 1.0f / vn;

    const size_t pix = (size_t)i * SDIM + j;
    const float n0 = nrm[((size_t)(b * 3 + 0)) * SS + pix];
    const float n1 = nrm[((size_t)(b * 3 + 1)) * SS + pix];
    const float n2 = nrm[((size_t)(b * 3 + 2)) * SS + pix];

    const float cos_t   = n0 * ldx + n1 * ldy + n2 * ldz;
    const float diffuse = fmaxf(cos_t, 0.0f);

    const float r0 = 2.0f * cos_t * n0 - ldx;
    const float r1 = 2.0f * cos_t * n1 - ldy;
    const float r2 = 2.0f * cos_t * n2 - ldz;
    float spec = fmaxf(vd0 * r0 + vd1 * r1 + vd2 * r2, 0.0f);
    const float gate  = (cos_t > 0.0f) ? 1.0f : 0.0f;
    const float maskv = (i >= 5 && i < SDIM - 5 && j >= 5 && j < SDIM - 5) ? 1.0f : 0.0f;
    spec = spec * gate * maskv;
    const float sclip = fminf(fmaxf(spec, 1e-7f), (float)(1.0 - 1e-7));
    const float sshad = fpow(sclip, spec_alpha);

    const float shadow_factor = fminf(fmaxf(1.0f - shadow_s, 0.1f), 1.0f);
    const float shading   = light_a + light_b * diffuse * shadow_factor;
    const float spec_term = spec_strength * light_b * sshad;

    const float inv_g = (float)(1.0 / 2.2);
#pragma unroll
    for (int cc = 0; cc < 3; ++cc) {
        const float a   = netA[((size_t)(b * 5 + cc)) * SS + pix];
        const float alb = fpow(ftanh(a) * 0.5f + 0.5f, 2.2f);
        float rim = alb * shading + spec_term;
        rim = fmaxf(rim, 1e-7f);
        out[((size_t)(b * 3 + cc)) * SS + pix] = fpow(rim, inv_g);
    }
}

extern "C" void kernel_launch(void* const* d_in, const int* in_sizes, int n_in,
                              void* d_out, int out_size, void* d_ws, size_t ws_size,
                              hipStream_t stream) {
    const float* netA  = (const float*)d_in[0];
    const float* netL  = (const float*)d_in[1];
    const float* nrm   = (const float*)d_in[2];
    const float* depth = (const float*)d_in[3];
    const float* light = (const float*)d_in[4];
    float* out = (float*)d_out;

    unsigned char* shmap = (unsigned char*)d_ws;   // 2 MiB

    shadow_march<<<2048, 256, 0, stream>>>(depth, light, shmap);
    compose_kernel<<<dim3(SDIM / 16, SDIM / 16, 32), 256, 0, stream>>>(netA, netL, nrm,
                                                                       light, shmap, out);
}

// Round 9
// 248.047 us; speedup vs baseline: 1.3759x; 1.3759x over previous
//
#include <hip/hip_runtime.h>

// ReconPhongIF: Phong shading with ray-marched shadows.
// R9 = R6 (masked persistent pools, 1 ray/lane, wave refill) + two fixes:
//  1) XCD-affine swizzle (R8-proven: FETCH 47->4.1 MB): batch =
//     ((blk&7)<<2)|((blk>>3)&3) pins each batch's 64 blocks to one XCD;
//     4 batches x 256KB image = 1MB resident per XCD L2.
//  2) Paired-step sampling: positions at steps t,t+1 are known before t's
//     outcome (pure adds), so both 4-load gather sets issue back-to-back
//     (8 outstanding loads/lane) before resolving t. 2x MLP with ZERO new
//     issue slots (R8 lesson: unmasked 2-ray ILP ballooned instructions).
//     Refill amortized to every pair. Waste: ~0.5 discarded samples/death.
// Decisions bit-identical to reference: same sequential fp32 pos+=step
// chain; guarded rcp+Newton fast sample; exact-IEEE reference fallback
// inside the guard band; z-exit floor 0.75-1e-6 provably decision-free.

#define SDIM 256
#define SS   (SDIM * SDIM)
#define TAN_T 0.08748866352592401      // tan(5 deg) in double
#define STEPC (2.0f / 255.0f)          // linspace(-1,1,256) step
#define POOL  1024                     // rays per block (4 rows)
#define MDV   (0.75f - 1e-6f)          // early-exit floor (depth >= 0.75 by domain)

// ---------------- exact reference test (bit-identical fallback) -------------
__device__ __forceinline__ bool exact_ref_test(float px, float py, float pz,
                                               const float* __restrict__ im) {
#pragma clang fp contract(off)
    const float T = (float)TAN_T;
    const float gx = (px / pz) / T;
    const float gy = (py / pz) / T;
    const float x = (gx + 1.0f) * 128.0f - 0.5f;
    const float y = (gy + 1.0f) * 128.0f - 0.5f;
    const float xo = floorf(x), yo = floorf(y);
    const float wx = x - xo, wy = y - yo;
    const int ex0 = (int)xo, ey0 = (int)yo;     // |coord| < 2400 -> cvt exact
    const int ex0c = min(max(ex0, 0), 255), ex1c = min(max(ex0 + 1, 0), 255);
    const int ey0c = min(max(ey0, 0), 255), ey1c = min(max(ey0 + 1, 0), 255);
    const float e00 = im[(ey0c << 8) + ex0c];
    const float e01 = im[(ey0c << 8) + ex1c];
    const float e10 = im[(ey1c << 8) + ex0c];
    const float e11 = im[(ey1c << 8) + ex1c];
    float s = e00 * (1.0f - wx) * (1.0f - wy);
    s = s + e01 * wx * (1.0f - wy);
    s = s + e10 * (1.0f - wx) * wy;
    s = s + e11 * wx * wy;
    return (s - pz) < 0.0f;
}

// fast sample; safe for pz >= 0.74 (|xf|,|yf| < ~2400 -> cvt defined)
struct Smp { float diff, guard; };
__device__ __forceinline__ Smp sample4(float px, float py, float pz,
                                       const float* __restrict__ im) {
#pragma clang fp contract(off)
    const float K = (float)(128.0 / TAN_T);
    float inv = __builtin_amdgcn_rcpf(pz);
    inv = fmaf(fmaf(-pz, inv, 1.0f), inv, inv);
    const float xf = fmaf(px * inv, K, 127.5f);
    const float yf = fmaf(py * inv, K, 127.5f);
    const float x0ff = floorf(xf);
    const float y0ff = floorf(yf);
    const float wxf = xf - x0ff;
    const float wyf = yf - y0ff;
    const int x0 = (int)x0ff;
    const int y0 = (int)y0ff;
    const int x0c = min(max(x0, 0), 255), x1c = min(max(x0 + 1, 0), 255);
    const int y0c = min(max(y0, 0), 255), y1c = min(max(y0 + 1, 0), 255);
    const int r0 = y0c << 8, r1 = y1c << 8;
    const float v00 = im[r0 + x0c];
    const float v01 = im[r0 + x1c];
    const float v10 = im[r1 + x0c];
    const float v11 = im[r1 + x1c];
    const float omx = 1.0f - wxf, omy = 1.0f - wyf;
    const float t0 = fmaf(v01, wxf, v00 * omx);
    const float t1 = fmaf(v11, wxf, v10 * omx);
    const float sF = fmaf(t1, wyf, t0 * omy);
    Smp s;
    s.diff  = sF - pz;
    // guard: pos err ~3e-7*|coord| x Lipschitz ~0.5/px, 4x margin
    s.guard = fmaf(fabsf(xf) + fabsf(yf), 6e-7f, 1e-5f);
    return s;
}

// ---------------- stage 1: persistent-pool march, paired steps --------------
__global__ __launch_bounds__(256) void shadow_march(const float* __restrict__ depth,
                                                    const float* __restrict__ light,
                                                    unsigned char* __restrict__ shmap) {
#pragma clang fp contract(off)
    const int blk = blockIdx.x;
    // XCD-affine: all 64 blocks of a batch share blk&7 -> same XCD L2
    const int b     = ((blk & 7) << 2) | ((blk >> 3) & 3);
    const int chunk = blk >> 5;            // 0..63
    const int rbase = chunk * POOL;        // 4 contiguous rows
    const float* im = depth + (size_t)b * SS;
    const int tid = threadIdx.x;
    const int lane = tid & 63;
    const float T = (float)TAN_T;

    // per-batch params (uniform; exact reference op order)
    const float lx = light[b * 2 + 0];
    const float ly = light[b * 2 + 1];
    float n2 = lx * lx;
    n2 = n2 + ly * ly;
    n2 = n2 + 1.0f;
    const float nr = sqrtf(n2);
    const float sx = (-(lx / nr)) / 256.0f;
    const float sy = (-(ly / nr)) / 256.0f;
    const float sz = (-(1.0f / nr)) / 256.0f;

    __shared__ float         dcache[POOL];
    __shared__ unsigned char res[POOL];
    __shared__ int           popc;
    if (tid == 0) popc = 0;
#pragma unroll
    for (int u = 0; u < POOL / 256; ++u) dcache[tid + u * 256] = im[rbase + tid + u * 256];
    __syncthreads();

    bool has = false, done = false;
    float px = 0.0f, py = 0.0f, pz = 1.0f;
    int rr = 0, krem = 0;

#pragma unroll 1
    while (true) {
        // ---- refill (once per pair) ----
        {
            const bool need = (!has) && (!done);
            const unsigned long long mneed = __ballot(need);
            if (mneed != 0ull) {           // wave-uniform branch
                if (need) {
                    const int leader = (int)__ffsll(mneed) - 1;
                    int base = 0;
                    if (lane == leader) base = atomicAdd(&popc, __popcll(mneed));
                    base = __shfl(base, leader, 64);
                    const int p = base + __popcll(mneed & ((1ull << (unsigned)lane) - 1ull));
                    if (p < POOL) {
                        const float d = dcache[p];
                        const int gidx = rbase + p;
                        const int i = gidx >> 8, j = gidx & 255;
                        const float cj = (-1.0f + (float)j * STEPC) * T;
                        const float ci = (-1.0f + (float)i * STEPC) * T;
                        px = cj * d; py = ci * d; pz = d;
                        rr = p; krem = 256; has = true;
                    } else {
                        done = true;
                    }
                }
            }
        }
        if (__ballot(has) == 0ull) break;
        if (has) {
            // ---- step t (commit) + step t+1 (speculative positions) ----
            px += sx; py += sy; pz += sz;
            const float qx = px + sx, qy = py + sy, qz = pz + sz;
            // both gather sets issue before any resolution (8 loads in flight)
            const Smp s1 = sample4(px, py, pz, im);
            const Smp s2 = sample4(qx, qy, qz, im);
            // ---- resolve step t ----
            bool dead = false, shv = false;
            if (pz <= MDV) {
                dead = true;               // z-exit: provably no trigger now or later
            } else {
                bool sh1 = s1.diff < 0.0f;
                if (__builtin_expect(fabsf(s1.diff) <= s1.guard, 0))
                    sh1 = exact_ref_test(px, py, pz, im);
                if (sh1) { dead = true; shv = true; }
            }
            // ---- resolve step t+1 (only if t survived) ----
            if (!dead) {
                px = qx; py = qy; pz = qz;
                if (pz <= MDV) {
                    dead = true;
                } else {
                    bool sh2 = s2.diff < 0.0f;
                    if (__builtin_expect(fabsf(s2.diff) <= s2.guard, 0))
                        sh2 = exact_ref_test(px, py, pz, im);
                    if (sh2) { dead = true; shv = true; }
                    else { krem -= 2; if (krem == 0) dead = true; }
                }
            }
            if (dead) {
                res[rr] = shv ? (unsigned char)1 : (unsigned char)0;
                has = false; px = 0.0f; py = 0.0f; pz = 1.0f;
            }
        }
    }
    __syncthreads();
    // coalesced flush: 1024 result bytes = 256 dwords
    ((unsigned int*)(shmap + (size_t)b * SS + rbase))[tid] = ((const unsigned int*)res)[tid];
}

// ---------------- stage 2: blur + Phong composition ----------------
__device__ __constant__ float W1[7] = {
    0.07015933f, 0.13107488f, 0.19071282f, 0.21610594f,
    0.19071282f, 0.13107488f, 0.07015933f
};

__device__ __forceinline__ float fpow(float x, float p) {
    return __builtin_amdgcn_exp2f(p * __builtin_amdgcn_logf(x));
}
__device__ __forceinline__ float ftanh(float x) {
    const float e = __builtin_amdgcn_exp2f(x * 2.8853900817779268f);
    return (e - 1.0f) * __builtin_amdgcn_rcpf(e + 1.0f);
}

__global__ __launch_bounds__(256) void compose_kernel(const float* __restrict__ netA,
                                                      const float* __restrict__ netL,
                                                      const float* __restrict__ nrm,
                                                      const float* __restrict__ light,
                                                      const unsigned char* __restrict__ shmap,
                                                      float* __restrict__ out) {
    __shared__ float tile[22][23];

    const int b  = blockIdx.z;
    const int tx = threadIdx.x & 15;
    const int ty = threadIdx.x >> 4;
    const int j0 = blockIdx.x * 16;
    const int i0 = blockIdx.y * 16;

    const unsigned char* shb = shmap + (size_t)b * SS;
    for (int idx = threadIdx.x; idx < 22 * 22; idx += 256) {
        const int r = idx / 22, c = idx - r * 22;
        const int gi = i0 - 3 + r, gj = j0 - 3 + c;
        float v = 0.0f;
        if (gi >= 0 && gi < SDIM && gj >= 0 && gj < SDIM) v = (float)shb[gi * SDIM + gj];
        tile[r][c] = v;
    }
    __syncthreads();

    const int i = i0 + ty;
    const int j = j0 + tx;

    float shadow_s = 0.0f;
#pragma unroll
    for (int dy = 0; dy < 7; ++dy) {
        float rs = 0.0f;
#pragma unroll
        for (int dx = 0; dx < 7; ++dx) rs += W1[dx] * tile[ty + dy][tx + dx];
        shadow_s += W1[dy] * rs;
    }

    const float l0 = tanhf(netL[b * 6 + 0]);
    const float l1 = tanhf(netL[b * 6 + 1]);
    const float l2 = tanhf(netL[b * 6 + 2]);
    const float l5 = tanhf(netL[b * 6 + 5]);
    const float e  = l0 * 0.5f + 0.5f;
    const float f  = e * (float)10.313708498984761 + 1.0f;
    const float spec_alpha    = f * f;
    const float spec_strength = (l5 * 0.5f + 0.5f) * 0.5f;
    const float light_a = l1 / 2.0f + 0.5f;
    const float light_b = l2 / 2.0f + 0.5f;

    const float lx = light[b * 2 + 0];
    const float ly = light[b * 2 + 1];
    const float ln = sqrtf(lx * lx + ly * ly + 1.0f);
    const float ldx = lx / ln, ldy = ly / ln, ldz = 1.0f / ln;

    const float T = (float)TAN_T;
    const float xsj = (-1.0f + (float)(SDIM - 1 - j) * STEPC) * T;
    const float xsi = (-1.0f + (float)(SDIM - 1 - i) * STEPC) * T;
    const float vn = sqrtf(xsj * xsj + xsi * xsi + 1.0f);
    const float vd0 = xsj / vn, vd1 = xsi / vn, vd2 = 1.0f / vn;

    const size_t pix = (size_t)i * SDIM + j;
    const float n0 = nrm[((size_t)(b * 3 + 0)) * SS + pix];
    const float n1 = nrm[((size_t)(b * 3 + 1)) * SS + pix];
    const float n2 = nrm[((size_t)(b * 3 + 2)) * SS + pix];

    const float cos_t   = n0 * ldx + n1 * ldy + n2 * ldz;
    const float diffuse = fmaxf(cos_t, 0.0f);

    const float r0 = 2.0f * cos_t * n0 - ldx;
    const float r1 = 2.0f * cos_t * n1 - ldy;
    const float r2 = 2.0f * cos_t * n2 - ldz;
    float spec = fmaxf(vd0 * r0 + vd1 * r1 + vd2 * r2, 0.0f);
    const float gate  = (cos_t > 0.0f) ? 1.0f : 0.0f;
    const float maskv = (i >= 5 && i < SDIM - 5 && j >= 5 && j < SDIM - 5) ? 1.0f : 0.0f;
    spec = spec * gate * maskv;
    const float sclip = fminf(fmaxf(spec, 1e-7f), (float)(1.0 - 1e-7));
    const float sshad = fpow(sclip, spec_alpha);

    const float shadow_factor = fminf(fmaxf(1.0f - shadow_s, 0.1f), 1.0f);
    const float shading   = light_a + light_b * diffuse * shadow_factor;
    const float spec_term = spec_strength * light_b * sshad;

    const float inv_g = (float)(1.0 / 2.2);
#pragma unroll
    for (int cc = 0; cc < 3; ++cc) {
        const float a   = netA[((size_t)(b * 5 + cc)) * SS + pix];
        const float alb = fpow(ftanh(a) * 0.5f + 0.5f, 2.2f);
        float rim = alb * shading + spec_term;
        rim = fmaxf(rim, 1e-7f);
        out[((size_t)(b * 3 + cc)) * SS + pix] = fpow(rim, inv_g);
    }
}

extern "C" void kernel_launch(void* const* d_in, const int* in_sizes, int n_in,
                              void* d_out, int out_size, void* d_ws, size_t ws_size,
                              hipStream_t stream) {
    const float* netA  = (const float*)d_in[0];
    const float* netL  = (const float*)d_in[1];
    const float* nrm   = (const float*)d_in[2];
    const float* depth = (const float*)d_in[3];
    const float* light = (const float*)d_in[4];
    float* out = (float*)d_out;

    unsigned char* shmap = (unsigned char*)d_ws;   // 2 MiB

    shadow_march<<<2048, 256, 0, stream>>>(depth, light, shmap);
    compose_kernel<<<dim3(SDIM / 16, SDIM / 16, 32), 256, 0, stream>>>(netA, netL, nrm,
                                                                       light, shmap, out);
}